// Round 8
// baseline (1175.247 us; speedup 1.0000x reference)
//
#include <hip/hip_runtime.h>
#include <hip/hip_bf16.h>

#define N_ATOMS 400000
#define MAX_D   4
#define NDEG_   5
#define B_GR    16384
#define NTASK   12
#define AT      256                 // bin alignment / affine tile
#define PADCAP  401408              // 1568 * 256 >= N + 5*(AT-1)
#define NSCR_FLOATS (PADCAP * 20)   // per-chunk scratch (32.1 MB each for D and E)
#define C1CAP   107008              // conv1 chunk atoms = ((NSCR_FLOATS/75)/256)*256

__device__ __forceinline__ float selu_f(float x) {
    const float a = 1.6732632423543772f, s = 1.0507009873554805f;
    return x > 0.f ? s * x : s * a * (__expf(x) - 1.f);
}

// ===================== degree-sort prep =====================
// ctr layout (ints): [0..4] counts, [5..9] cursor, [10..15] bin offsets
__global__ void zero_kernel(int* ctr) {
    if (threadIdx.x < 10) ctr[threadIdx.x] = 0;
}

__launch_bounds__(256)
__global__ void fill_kernel(int* idx, int* degs_s) {
    const int e = blockIdx.x * 256 + threadIdx.x;
    if (e < PADCAP) { idx[e] = -1; degs_s[e] = -1; }
}

__launch_bounds__(256)
__global__ void hist_kernel(const int* __restrict__ deg, int* ctr) {
    __shared__ int h[NDEG_];
    if (threadIdx.x < NDEG_) h[threadIdx.x] = 0;
    __syncthreads();
    for (int i = blockIdx.x * 256 + threadIdx.x; i < N_ATOMS; i += gridDim.x * 256)
        atomicAdd(&h[deg[i]], 1);
    __syncthreads();
    if (threadIdx.x < NDEG_ && h[threadIdx.x]) atomicAdd(&ctr[threadIdx.x], h[threadIdx.x]);
}

__global__ void offsets_kernel(int* ctr) {
    if (threadIdx.x == 0) {
        int run = 0;
        for (int d = 0; d < NDEG_; ++d) {
            ctr[10 + d] = run;
            run += ctr[d];
            run = (run + AT - 1) & ~(AT - 1);
        }
        ctr[15] = run;
    }
}

// Hierarchical scatter: per-block LDS histogram -> ONE global atomicAdd per
// (block, degree) -> intra-block rank from LDS counter.
__launch_bounds__(256)
__global__ void scatter_kernel(const int* __restrict__ deg, int* ctr,
                               int* idx, int* rank, int* degs_s) {
    __shared__ int h[NDEG_];
    __shared__ int base[NDEG_];
    const int i = blockIdx.x * 256 + threadIdx.x;
    const int d = (i < N_ATOMS) ? deg[i] : -1;
    if (threadIdx.x < NDEG_) h[threadIdx.x] = 0;
    __syncthreads();
    int intra = 0;
    if (i < N_ATOMS) intra = atomicAdd(&h[d], 1);            // LDS atomic
    __syncthreads();
    if (threadIdx.x < NDEG_ && h[threadIdx.x] > 0)
        base[threadIdx.x] = atomicAdd(&ctr[5 + threadIdx.x], h[threadIdx.x]);
    __syncthreads();
    if (i < N_ATOMS) {
        const int p = ctr[10 + d] + base[d] + intra;
        idx[p] = i;
        rank[i] = p;
        degs_s[p] = d;
    }
}

// Emits BOTH sorted-rank neighbors (layers 2-4) and original-id neighbors (conv1).
__launch_bounds__(256)
__global__ void nbrprep_kernel(const int* __restrict__ nbr, const int* __restrict__ rank,
                               int4* __restrict__ nbrs_s, int4* __restrict__ nbro_s) {
    const int i = blockIdx.x * 256 + threadIdx.x;
    if (i >= N_ATOMS) return;
    const int p = rank[i];
    const int4 nb = *reinterpret_cast<const int4*>(nbr + (size_t)i * MAX_D);
    nbro_s[p] = nb;
    nbrs_s[p] = make_int4(rank[nb.x], rank[nb.y], rank[nb.z], rank[nb.w]);
}

// ===================== conv1 prep: fused permute + gather + transpose =====================
// Block = 64 atoms. Phase A: stage self row + masked 4-neighbor sum into LDS
// tiles (rows padded to 77 -> conflict-free). Phase B: write both TRANSPOSED
// [f][atom] with atom-across-lanes (coalesced 256B stores). The downstream
// affine then reads lane-coalesced, killing the 9x line re-fetch of
// per-lane-row reads (R4/R7: 600+ MB FETCH on 64 MB of data).
__launch_bounds__(256)
__global__ void prep1_kernel(const float* __restrict__ af,
                             const int4*  __restrict__ nbro,
                             const int*   __restrict__ degs_s,
                             const int*   __restrict__ idx,
                             float*       __restrict__ afs_t,   // [75][cap]
                             float*       __restrict__ nsum_t,  // [75][cap]
                             int p0, int cap)
{
    __shared__ float xt[64][77];
    __shared__ float nt[64][77];
    __shared__ int   s_a[64];
    __shared__ int   s_d[64];
    __shared__ int4  s_nb[64];

    const int pb = p0 + blockIdx.x * 64;
    const int tid = threadIdx.x;

    if (tid < 64) {
        const int p = pb + tid;
        int a = idx[p];
        s_a[tid] = (a < 0) ? 0 : a;
        s_d[tid] = degs_s[p];
        s_nb[tid] = nbro[p];
    }
    __syncthreads();

    // Phase A: e-loop atom-major, f across lanes -> coalesced row reads.
    for (int e = tid; e < 64 * 75; e += 256) {
        const int al = e / 75, f = e - al * 75;
        const int d = s_d[al];
        xt[al][f] = af[(size_t)s_a[al] * 75 + f];
        float s = 0.f;
        if (d > 0) {
            const int4 nb = s_nb[al];
            s += af[(size_t)nb.x * 75 + f];
            if (d > 1) s += af[(size_t)nb.y * 75 + f];
            if (d > 2) s += af[(size_t)nb.z * 75 + f];
            if (d > 3) s += af[(size_t)nb.w * 75 + f];
        }
        nt[al][f] = s;
    }
    __syncthreads();

    // Phase B: transposed write, atoms across lanes -> coalesced stores.
    const int cb = pb - p0;    // chunk-local atom base
    for (int e = tid; e < 75 * 64; e += 256) {
        const int fi = e >> 6, al = e & 63;
        afs_t[(size_t)fi * cap + cb + al] = xt[al][fi];
        nsum_t[(size_t)fi * cap + cb + al] = nt[al][fi];
    }
}

// ===================== conv1 affine on transposed inputs =====================
// Degree-uniform 256-tiles; lane = atom; every load is lane-coalesced
// (one 256B transaction per wave per f). Wave-uniform scalar weights, no LDS.
__launch_bounds__(256)
__global__ void affine_t(const float* __restrict__ afs_t,
                         const float* __restrict__ nsum_t,
                         const float* __restrict__ Ws,
                         const float* __restrict__ Wn,
                         const float* __restrict__ bias,
                         const int*   __restrict__ degs_s,
                         float*       __restrict__ outs,
                         int p0, int cap)
{
    const int tile_base = p0 + blockIdx.x * AT;
    const int dfirst = degs_s[tile_base];
    if (dfirst < 0) return;                       // whole tile is padding
    const int d = __builtin_amdgcn_readfirstlane(dfirst);

    const float* __restrict__ wsd = Ws + d * 75 * 15;
    const float* __restrict__ wnd = Wn + d * 75 * 15;
    const float* __restrict__ bb  = bias + d * 15;

    const int p = tile_base + threadIdx.x;
    const int c = p - p0;                         // chunk-local column

    float acc[15];
    #pragma unroll
    for (int o = 0; o < 15; ++o) acc[o] = bb[o];

    for (int f = 0; f < 75; ++f) {
        const float xv = afs_t[(size_t)f * cap + c];
        const float nv = nsum_t[(size_t)f * cap + c];
        const float* __restrict__ wsf = wsd + f * 15;
        const float* __restrict__ wnf = wnd + f * 15;
        #pragma unroll
        for (int o = 0; o < 15; ++o)
            acc[o] = fmaf(xv, wsf[o], fmaf(nv, wnf[o], acc[o]));
    }

    float* __restrict__ orow = outs + (size_t)p * 15;
    #pragma unroll
    for (int o = 0; o < 15; ++o) orow[o] = selu_f(acc[o]);
}

// ===================== gather (layers 2-4): masked neighbor sum =====================
template<int FI>
__launch_bounds__(256)
__global__ void gather_s(const float* __restrict__ x,
                         const int4*  __restrict__ nbrs,
                         const int*   __restrict__ degs_s,
                         float*       __restrict__ nsum,
                         int p0, int total /* = cnt*FI */)
{
    for (int e = blockIdx.x * 256 + threadIdx.x; e < total; e += gridDim.x * 256) {
        const int pl = e / FI, f = e - pl * FI;
        const int p = p0 + pl;
        const int d = degs_s[p];
        float s = 0.f;
        if (d > 0) {
            const int4 nb = nbrs[p];
            s += x[(size_t)nb.x * FI + f];
            if (d > 1) s += x[(size_t)nb.y * FI + f];
            if (d > 2) s += x[(size_t)nb.z * FI + f];
            if (d > 3) s += x[(size_t)nb.w * FI + f];
        }
        nsum[e] = s;
    }
}

// ===================== affine (layers 2-4): direct per-lane rows =====================
// Small rows (60-108B) -> no line-thrash; wave-uniform scalar weights; no LDS.
template<int FI, int FO>
__launch_bounds__(256)
__global__ void affine_d(const float* __restrict__ x, int x0,
                         const float* __restrict__ nsum,
                         const float* __restrict__ Ws,
                         const float* __restrict__ Wn,
                         const float* __restrict__ bias,
                         const int*   __restrict__ degs_s,
                         float*       __restrict__ outs,
                         int p0)
{
    const int tile_base = p0 + blockIdx.x * AT;
    const int dfirst = degs_s[tile_base];
    if (dfirst < 0) return;                       // whole tile is padding
    const int d = __builtin_amdgcn_readfirstlane(dfirst);

    const float* __restrict__ wsd = Ws + d * FI * FO;
    const float* __restrict__ wnd = Wn + d * FI * FO;
    const float* __restrict__ bb  = bias + d * FO;

    const int p = tile_base + threadIdx.x;

    float acc[FO];
    #pragma unroll
    for (int o = 0; o < FO; ++o) acc[o] = bb[o];

    const float* __restrict__ xr = x + (size_t)(p - x0) * FI;
    const float* __restrict__ nr = nsum + (size_t)(p - p0) * FI;

    for (int f = 0; f < FI; ++f) {
        const float xv = xr[f];
        const float nv = nr[f];
        const float* __restrict__ wsf = wsd + f * FO;
        const float* __restrict__ wnf = wnd + f * FO;
        #pragma unroll
        for (int o = 0; o < FO; ++o)
            acc[o] = fmaf(xv, wsf[o], fmaf(nv, wnf[o], acc[o]));
    }

    float* __restrict__ orow = outs + (size_t)p * FO;
    #pragma unroll
    for (int o = 0; o < FO; ++o) orow[o] = selu_f(acc[o]);
}

static void run_conv1(const float* af, const float* Ws, const float* Wn, const float* b,
                      const int4* nbro_s, const int* degs_s, const int* idx,
                      float* outs, float* nsum_t, float* afs_t, hipStream_t stream)
{
    for (int p0 = 0; p0 < PADCAP; p0 += C1CAP) {
        const int cnt = (PADCAP - p0) < C1CAP ? (PADCAP - p0) : C1CAP;
        prep1_kernel<<<cnt / 64, 256, 0, stream>>>(af, nbro_s, degs_s, idx,
                                                   afs_t, nsum_t, p0, C1CAP);
        affine_t<<<cnt / AT, AT, 0, stream>>>(afs_t, nsum_t, Ws, Wn, b, degs_s,
                                              outs, p0, C1CAP);
    }
}

template<int FI, int FO>
static void run_conv(const float* x, const float* Ws, const float* Wn, const float* b,
                     const int4* nbrs_s, const int* degs_s,
                     float* outs, float* nscr, hipStream_t stream)
{
    const int cap = ((NSCR_FLOATS / FI) / AT) * AT;
    for (int p0 = 0; p0 < PADCAP; p0 += cap) {
        const int cnt = (PADCAP - p0) < cap ? (PADCAP - p0) : cap;
        const int gtot = cnt * FI;
        int gblocks = (gtot + 255) / 256; if (gblocks > 8192) gblocks = 8192;
        gather_s<FI><<<gblocks, 256, 0, stream>>>(x, nbrs_s, degs_s, nscr, p0, gtot);
        affine_d<FI, FO><<<cnt / AT, AT, 0, stream>>>(x, 0, nscr, Ws, Wn, b, degs_s, outs, p0);
    }
}

// ===================== GraphGather readout + softmax head =====================
__launch_bounds__(64)
__global__ void readout_kernel(const float* __restrict__ x4s,
                               const int*   __restrict__ rank,
                               const int*   __restrict__ mem,
                               const float* __restrict__ Wd2,
                               const float* __restrict__ bd2,
                               float*       __restrict__ p)
{
    const int g = blockIdx.x;
    const int t = threadIdx.x;

    int lo = 0, hi = N_ATOMS;                    // lower_bound(g)
    while (lo < hi) { int mid = (lo + hi) >> 1; if (mem[mid] < g) lo = mid + 1; else hi = mid; }
    int lo2 = lo, hi2 = N_ATOMS;                 // lower_bound(g+1)
    while (lo2 < hi2) { int mid = (lo2 + hi2) >> 1; if (mem[mid] < g + 1) lo2 = mid + 1; else hi2 = mid; }

    __shared__ float r[72];
    if (t < 36) {
        float s = 0.f, m = -3.4e38f;
        for (int a = lo; a < lo2; ++a) {
            const int rr = rank[a];
            float v = x4s[(size_t)rr * 36 + t];
            s += v;
            m = fmaxf(m, v);
        }
        if (lo2 == lo) m = 0.f;                  // empty graph -> 0
        r[t]      = selu_f(s);
        r[36 + t] = selu_f(m);
    }
    __syncthreads();
    if (t < 24) {
        float acc = bd2[t];
        #pragma unroll
        for (int f = 0; f < 72; ++f) acc += r[f] * Wd2[f * 24 + t];
        float part = __shfl_xor(acc, 1);
        p[g * 24 + t] = 1.f / (1.f + __expf(part - acc));
    }
}

__launch_bounds__(256)
__global__ void dense1_kernel(const float* __restrict__ p,
                              const float* __restrict__ Wl1,
                              const float* __restrict__ bl1,
                              float*       __restrict__ y1)
{
    const int idx = blockIdx.x * 256 + threadIdx.x;
    if (idx >= B_GR * 96) return;
    const int row = idx / 96, c = idx - row * 96;
    float acc = bl1[c];
    const float* pr = p + row * 24;
    #pragma unroll
    for (int f = 0; f < 24; ++f) acc += pr[f] * Wl1[f * 96 + c];
    y1[idx] = acc;
}

template<int C>
__launch_bounds__(256)
__global__ void stats_kernel(const float* __restrict__ y, float* __restrict__ st)
{
    const int c = blockIdx.x;
    float s = 0.f, q = 0.f;
    for (int r = threadIdx.x; r < B_GR; r += 256) {
        const float v = y[r * C + c];
        s += v; q += v * v;
    }
    __shared__ float ss[256], qq[256];
    ss[threadIdx.x] = s; qq[threadIdx.x] = q;
    __syncthreads();
    for (int off = 128; off > 0; off >>= 1) {
        if (threadIdx.x < off) {
            ss[threadIdx.x] += ss[threadIdx.x + off];
            qq[threadIdx.x] += qq[threadIdx.x + off];
        }
        __syncthreads();
    }
    if (threadIdx.x == 0) {
        const float mean = ss[0] / (float)B_GR;
        const float var  = qq[0] / (float)B_GR - mean * mean;
        st[c]     = mean;
        st[C + c] = rsqrtf(var + 1e-5f);
    }
}

__launch_bounds__(256)
__global__ void dense2_kernel(const float* __restrict__ y1,
                              const float* __restrict__ st1,
                              const float* __restrict__ g1,
                              const float* __restrict__ be1,
                              const float* __restrict__ Wl2,
                              const float* __restrict__ bl2,
                              float*       __restrict__ y2)
{
    __shared__ float h[4 * 96];
    const int r0 = blockIdx.x * 4;
    for (int e = threadIdx.x; e < 4 * 96; e += 256) {
        const int rr = e / 96, c = e - rr * 96;
        float v = y1[(r0 + rr) * 96 + c];
        v = (v - st1[c]) * st1[96 + c] * g1[c] + be1[c];
        h[e] = fmaxf(v, 0.f);
    }
    __syncthreads();
    for (int e = threadIdx.x; e < 4 * 63; e += 256) {
        const int rr = e / 63, o = e - rr * 63;
        float acc = bl2[o];
        #pragma unroll
        for (int f = 0; f < 96; ++f) acc += h[rr * 96 + f] * Wl2[f * 63 + o];
        y2[(r0 + rr) * 63 + o] = acc;
    }
}

__launch_bounds__(320)
__global__ void dense3_kernel(const float* __restrict__ y2,
                              const float* __restrict__ st2,
                              const float* __restrict__ g2,
                              const float* __restrict__ be2,
                              const float* __restrict__ Wl3,
                              const float* __restrict__ bl3,
                              float*       __restrict__ out)
{
    __shared__ float h[2 * 63];
    const int r0 = blockIdx.x * 2;
    for (int e = threadIdx.x; e < 2 * 63; e += 320) {
        const int rr = e / 63, c = e - rr * 63;
        float v = y2[(r0 + rr) * 63 + c];
        v = (v - st2[c]) * st2[63 + c] * g2[c] + be2[c];
        h[e] = fmaxf(v, 0.f);
    }
    __syncthreads();
    for (int e = threadIdx.x; e < 2 * 138; e += 320) {
        const int rr = e / 138, o = e - rr * 138;
        float acc = bl3[o];
        #pragma unroll
        for (int f = 0; f < 63; ++f) acc += h[rr * 63 + f] * Wl3[f * 138 + o];
        out[(r0 + rr) * 138 + o] = 1.f / (1.f + __expf(-acc));
    }
}

extern "C" void kernel_launch(void* const* d_in, const int* in_sizes, int n_in,
                              void* d_out, int out_size, void* d_ws, size_t ws_size,
                              hipStream_t stream)
{
    (void)in_sizes; (void)n_in; (void)out_size; (void)ws_size;

    const float* af  = (const float*)d_in[0];
    const float* Ws1 = (const float*)d_in[1];
    const float* Wn1 = (const float*)d_in[2];
    const float* b1  = (const float*)d_in[3];
    const float* Ws2 = (const float*)d_in[4];
    const float* Wn2 = (const float*)d_in[5];
    const float* b2  = (const float*)d_in[6];
    const float* Ws3 = (const float*)d_in[7];
    const float* Wn3 = (const float*)d_in[8];
    const float* b3  = (const float*)d_in[9];
    const float* Ws4 = (const float*)d_in[10];
    const float* Wn4 = (const float*)d_in[11];
    const float* b4  = (const float*)d_in[12];
    const float* Wd2 = (const float*)d_in[13];
    const float* bd2 = (const float*)d_in[14];
    const float* Wl1 = (const float*)d_in[15];
    const float* bl1 = (const float*)d_in[16];
    const float* g1  = (const float*)d_in[17];
    const float* be1 = (const float*)d_in[18];
    const float* Wl2 = (const float*)d_in[19];
    const float* bl2 = (const float*)d_in[20];
    const float* g2  = (const float*)d_in[21];
    const float* be2 = (const float*)d_in[22];
    const float* Wl3 = (const float*)d_in[23];
    const float* bl3 = (const float*)d_in[24];
    const int*   nbr = (const int*)d_in[25];
    const int*   deg = (const int*)d_in[26];
    const int*   mem = (const int*)d_in[27];

    float* ws = (float*)d_ws;
    // Regions (floats):
    //   A: PADCAP*27  x1 (conv1-2) then x3 (conv3-4); head scratch after conv4
    //   B: PADCAP*36  x2 (conv2-3) then x4 (conv4+)
    //   D: PADCAP*20  nsum scratch (layers 2-4) / nsum_t (conv1, [75][C1CAP])
    //   E: PADCAP*20  afs_t (conv1 transposed self rows, [75][C1CAP])
    float* A = ws;
    float* B = A + (size_t)PADCAP * 27;
    float* D = B + (size_t)PADCAP * 36;
    float* E = D + (size_t)PADCAP * 20;
    int*   idx    = (int*)(E + (size_t)PADCAP * 20);    // PADCAP
    int*   rank   = idx + PADCAP;                       // N_ATOMS
    int*   degs_s = rank + N_ATOMS;                     // PADCAP
    int4*  nbrs_s = (int4*)(degs_s + PADCAP);           // PADCAP int4 (sorted ranks)
    int4*  nbro_s = nbrs_s + PADCAP;                    // PADCAP int4 (original ids)
    int*   ctr    = (int*)(nbro_s + PADCAP);            // 16 ints

    float* x1 = A;
    float* x2 = B;
    float* x3 = A;
    float* x4 = B;
    float* p   = A;                          // head scratch reuses A (x3 dead after conv4)
    float* y1  = A + 393216;                 // B_GR*96
    float* y2  = A + 393216 + 1572864;       // B_GR*63
    float* st1 = A + 393216 + 1572864 + 1032192;        // 192
    float* st2 = st1 + 192;                              // 126

    // ---- degree-sort prep (permutation may vary run-to-run; per-atom math identical) ----
    zero_kernel<<<1, 16, 0, stream>>>(ctr);
    fill_kernel<<<PADCAP / 256, 256, 0, stream>>>(idx, degs_s);
    hist_kernel<<<1024, 256, 0, stream>>>(deg, ctr);
    offsets_kernel<<<1, 1, 0, stream>>>(ctr);
    scatter_kernel<<<(N_ATOMS + 255) / 256, 256, 0, stream>>>(deg, ctr, idx, rank, degs_s);
    nbrprep_kernel<<<(N_ATOMS + 255) / 256, 256, 0, stream>>>(nbr, rank, nbrs_s, nbro_s);

    // ---- conv stack ----
    run_conv1(af, Ws1, Wn1, b1, nbro_s, degs_s, idx, x1, D, E, stream);
    run_conv<15, 20>(x1, Ws2, Wn2, b2, nbrs_s, degs_s, x2, D, stream);
    run_conv<20, 27>(x2, Ws3, Wn3, b3, nbrs_s, degs_s, x3, D, stream);
    run_conv<27, 36>(x3, Ws4, Wn4, b4, nbrs_s, degs_s, x4, D, stream);

    readout_kernel<<<B_GR, 64, 0, stream>>>(x4, rank, mem, Wd2, bd2, p);

    dense1_kernel<<<(B_GR * 96) / 256, 256, 0, stream>>>(p, Wl1, bl1, y1);
    stats_kernel<96><<<96, 256, 0, stream>>>(y1, st1);
    dense2_kernel<<<B_GR / 4, 256, 0, stream>>>(y1, st1, g1, be1, Wl2, bl2, y2);
    stats_kernel<63><<<63, 256, 0, stream>>>(y2, st2);
    dense3_kernel<<<B_GR / 2, 320, 0, stream>>>(y2, st2, g2, be2, Wl3, bl3, (float*)d_out);
}

// Round 9
// 989.829 us; speedup vs baseline: 1.1873x; 1.1873x over previous
//
#include <hip/hip_runtime.h>
#include <hip/hip_bf16.h>

#define N_ATOMS 400000
#define MAX_D   4
#define NDEG_   5
#define B_GR    16384
#define NTASK   12
#define AT      256                 // bin alignment / affine tile
#define PADCAP  401408              // 1568 * 256 >= N + 5*(AT-1)
#define NSCR_FLOATS (PADCAP * 20)   // per-chunk scratch (32.1 MB each for D and E)
#define C1CAP   107008              // conv1 chunk atoms = ((NSCR_FLOATS/75)/256)*256

__device__ __forceinline__ float selu_f(float x) {
    const float a = 1.6732632423543772f, s = 1.0507009873554805f;
    return x > 0.f ? s * x : s * a * (__expf(x) - 1.f);
}

// ===================== degree-sort prep =====================
// ctr layout (ints): [0..4] counts, [5..9] cursor, [10..15] bin offsets
__global__ void zero_kernel(int* ctr) {
    if (threadIdx.x < 10) ctr[threadIdx.x] = 0;
}

__launch_bounds__(256)
__global__ void fill_kernel(int* idx, int* degs_s) {
    const int e = blockIdx.x * 256 + threadIdx.x;
    if (e < PADCAP) { idx[e] = -1; degs_s[e] = -1; }
}

__launch_bounds__(256)
__global__ void hist_kernel(const int* __restrict__ deg, int* ctr) {
    __shared__ int h[NDEG_];
    if (threadIdx.x < NDEG_) h[threadIdx.x] = 0;
    __syncthreads();
    for (int i = blockIdx.x * 256 + threadIdx.x; i < N_ATOMS; i += gridDim.x * 256)
        atomicAdd(&h[deg[i]], 1);
    __syncthreads();
    if (threadIdx.x < NDEG_ && h[threadIdx.x]) atomicAdd(&ctr[threadIdx.x], h[threadIdx.x]);
}

__global__ void offsets_kernel(int* ctr) {
    if (threadIdx.x == 0) {
        int run = 0;
        for (int d = 0; d < NDEG_; ++d) {
            ctr[10 + d] = run;
            run += ctr[d];
            run = (run + AT - 1) & ~(AT - 1);
        }
        ctr[15] = run;
    }
}

// Hierarchical scatter: per-block LDS histogram -> ONE global atomicAdd per
// (block, degree) -> intra-block rank from LDS counter.
__launch_bounds__(256)
__global__ void scatter_kernel(const int* __restrict__ deg, int* ctr,
                               int* idx, int* rank, int* degs_s) {
    __shared__ int h[NDEG_];
    __shared__ int base[NDEG_];
    const int i = blockIdx.x * 256 + threadIdx.x;
    const int d = (i < N_ATOMS) ? deg[i] : -1;
    if (threadIdx.x < NDEG_) h[threadIdx.x] = 0;
    __syncthreads();
    int intra = 0;
    if (i < N_ATOMS) intra = atomicAdd(&h[d], 1);            // LDS atomic
    __syncthreads();
    if (threadIdx.x < NDEG_ && h[threadIdx.x] > 0)
        base[threadIdx.x] = atomicAdd(&ctr[5 + threadIdx.x], h[threadIdx.x]);
    __syncthreads();
    if (i < N_ATOMS) {
        const int p = ctr[10 + d] + base[d] + intra;
        idx[p] = i;
        rank[i] = p;
        degs_s[p] = d;
    }
}

// Emits BOTH sorted-rank neighbors (layers 2-4) and original-id neighbors (conv1).
__launch_bounds__(256)
__global__ void nbrprep_kernel(const int* __restrict__ nbr, const int* __restrict__ rank,
                               int4* __restrict__ nbrs_s, int4* __restrict__ nbro_s) {
    const int i = blockIdx.x * 256 + threadIdx.x;
    if (i >= N_ATOMS) return;
    const int p = rank[i];
    const int4 nb = *reinterpret_cast<const int4*>(nbr + (size_t)i * MAX_D);
    nbro_s[p] = nb;
    nbrs_s[p] = make_int4(rank[nb.x], rank[nb.y], rank[nb.z], rank[nb.w]);
}

// ===================== conv prep: fused (permute+)gather + transpose =====================
// Block = 64 atoms. Phase A: stage self row + masked 4-neighbor sum into LDS
// tiles (rows padded to odd FIP -> conflict-free); coalesced row reads (f
// across lanes). Phase B: write both TRANSPOSED [f][atom] with atoms across
// lanes (coalesced 256B stores). The downstream affine reads lane-coalesced,
// killing the FI-times line re-fetch of per-lane-row reads (R4/R7/R8:
// 600+ MB FETCH on ~50 MB of data, all layers).
template<int FI, int FIP, bool FIRST>
__launch_bounds__(256)
__global__ void prep_kernel(const float* __restrict__ x,     // FIRST: af (orig order), else x_prev (sorted rows)
                            const int4*  __restrict__ nbr_,  // FIRST: original ids, else sorted ranks
                            const int*   __restrict__ degs_s,
                            const int*   __restrict__ idx,
                            float*       __restrict__ x_t,    // [FI][cap]
                            float*       __restrict__ nsum_t, // [FI][cap]
                            int p0, int cap)
{
    __shared__ float xt[64][FIP];
    __shared__ float nt[64][FIP];
    __shared__ int   s_a[64];
    __shared__ int   s_d[64];
    __shared__ int4  s_nb[64];

    const int pb = p0 + blockIdx.x * 64;
    const int tid = threadIdx.x;

    if (tid < 64) {
        const int p = pb + tid;
        if (FIRST) {
            int a = idx[p];
            s_a[tid] = (a < 0) ? 0 : a;
        } else {
            s_a[tid] = p;
        }
        s_d[tid] = degs_s[p];
        s_nb[tid] = nbr_[p];
    }
    __syncthreads();

    // Phase A: e-loop atom-major, f across lanes -> coalesced row reads.
    for (int e = tid; e < 64 * FI; e += 256) {
        const int al = e / FI, f = e - al * FI;
        const int d = s_d[al];
        xt[al][f] = x[(size_t)s_a[al] * FI + f];
        float s = 0.f;
        if (d > 0) {
            const int4 nb = s_nb[al];
            s += x[(size_t)nb.x * FI + f];
            if (d > 1) s += x[(size_t)nb.y * FI + f];
            if (d > 2) s += x[(size_t)nb.z * FI + f];
            if (d > 3) s += x[(size_t)nb.w * FI + f];
        }
        nt[al][f] = s;
    }
    __syncthreads();

    // Phase B: transposed write, atoms across lanes -> coalesced stores.
    const int cb = pb - p0;    // chunk-local atom base
    for (int e = tid; e < FI * 64; e += 256) {
        const int fi = e >> 6, al = e & 63;
        x_t[(size_t)fi * cap + cb + al] = xt[al][fi];
        nsum_t[(size_t)fi * cap + cb + al] = nt[al][fi];
    }
}

// ===================== affine on transposed inputs (all layers) =====================
// Degree-uniform 256-tiles; lane = atom; every load is lane-coalesced (one
// 256B transaction per wave per f, each 64B line fully consumed in one
// instruction -> zero re-fetch). Wave-uniform scalar weights, acc[FO] in
// registers, no LDS. Output written row-major (next prep / readout want rows;
// consecutive lanes' rows are contiguous -> writes near-coalesced).
template<int FI, int FO>
__launch_bounds__(256)
__global__ void affine_tg(const float* __restrict__ x_t,
                          const float* __restrict__ nsum_t,
                          const float* __restrict__ Ws,
                          const float* __restrict__ Wn,
                          const float* __restrict__ bias,
                          const int*   __restrict__ degs_s,
                          float*       __restrict__ outs,
                          int p0, int cap)
{
    const int tile_base = p0 + blockIdx.x * AT;
    const int dfirst = degs_s[tile_base];
    if (dfirst < 0) return;                       // whole tile is padding
    const int d = __builtin_amdgcn_readfirstlane(dfirst);

    const float* __restrict__ wsd = Ws + d * FI * FO;
    const float* __restrict__ wnd = Wn + d * FI * FO;
    const float* __restrict__ bb  = bias + d * FO;

    const int p = tile_base + threadIdx.x;
    const int c = p - p0;                         // chunk-local column

    float acc[FO];
    #pragma unroll
    for (int o = 0; o < FO; ++o) acc[o] = bb[o];

    for (int f = 0; f < FI; ++f) {
        const float xv = x_t[(size_t)f * cap + c];
        const float nv = nsum_t[(size_t)f * cap + c];
        const float* __restrict__ wsf = wsd + f * FO;
        const float* __restrict__ wnf = wnd + f * FO;
        #pragma unroll
        for (int o = 0; o < FO; ++o)
            acc[o] = fmaf(xv, wsf[o], fmaf(nv, wnf[o], acc[o]));
    }

    float* __restrict__ orow = outs + (size_t)p * FO;
    #pragma unroll
    for (int o = 0; o < FO; ++o) orow[o] = selu_f(acc[o]);
}

template<int FI, int FIP, int FO, bool FIRST>
static void run_convT(const float* x, const float* Ws, const float* Wn, const float* b,
                      const int4* nbr_, const int* degs_s, const int* idx,
                      float* outs, float* x_t, float* nsum_t, hipStream_t stream)
{
    int cap = ((NSCR_FLOATS / FI) / AT) * AT;     // chunk atoms (multiple of 256)
    if (cap > PADCAP) cap = PADCAP;
    for (int p0 = 0; p0 < PADCAP; p0 += cap) {
        const int cnt = (PADCAP - p0) < cap ? (PADCAP - p0) : cap;
        prep_kernel<FI, FIP, FIRST><<<cnt / 64, 256, 0, stream>>>
            (x, nbr_, degs_s, idx, x_t, nsum_t, p0, cap);
        affine_tg<FI, FO><<<cnt / AT, AT, 0, stream>>>
            (x_t, nsum_t, Ws, Wn, b, degs_s, outs, p0, cap);
    }
}

// ===================== GraphGather readout + softmax head =====================
__launch_bounds__(64)
__global__ void readout_kernel(const float* __restrict__ x4s,
                               const int*   __restrict__ rank,
                               const int*   __restrict__ mem,
                               const float* __restrict__ Wd2,
                               const float* __restrict__ bd2,
                               float*       __restrict__ p)
{
    const int g = blockIdx.x;
    const int t = threadIdx.x;

    int lo = 0, hi = N_ATOMS;                    // lower_bound(g)
    while (lo < hi) { int mid = (lo + hi) >> 1; if (mem[mid] < g) lo = mid + 1; else hi = mid; }
    int lo2 = lo, hi2 = N_ATOMS;                 // lower_bound(g+1)
    while (lo2 < hi2) { int mid = (lo2 + hi2) >> 1; if (mem[mid] < g + 1) lo2 = mid + 1; else hi2 = mid; }

    __shared__ float r[72];
    if (t < 36) {
        float s = 0.f, m = -3.4e38f;
        for (int a = lo; a < lo2; ++a) {
            const int rr = rank[a];
            float v = x4s[(size_t)rr * 36 + t];
            s += v;
            m = fmaxf(m, v);
        }
        if (lo2 == lo) m = 0.f;                  // empty graph -> 0
        r[t]      = selu_f(s);
        r[36 + t] = selu_f(m);
    }
    __syncthreads();
    if (t < 24) {
        float acc = bd2[t];
        #pragma unroll
        for (int f = 0; f < 72; ++f) acc += r[f] * Wd2[f * 24 + t];
        float part = __shfl_xor(acc, 1);
        p[g * 24 + t] = 1.f / (1.f + __expf(part - acc));
    }
}

__launch_bounds__(256)
__global__ void dense1_kernel(const float* __restrict__ p,
                              const float* __restrict__ Wl1,
                              const float* __restrict__ bl1,
                              float*       __restrict__ y1)
{
    const int idx = blockIdx.x * 256 + threadIdx.x;
    if (idx >= B_GR * 96) return;
    const int row = idx / 96, c = idx - row * 96;
    float acc = bl1[c];
    const float* pr = p + row * 24;
    #pragma unroll
    for (int f = 0; f < 24; ++f) acc += pr[f] * Wl1[f * 96 + c];
    y1[idx] = acc;
}

template<int C>
__launch_bounds__(256)
__global__ void stats_kernel(const float* __restrict__ y, float* __restrict__ st)
{
    const int c = blockIdx.x;
    float s = 0.f, q = 0.f;
    for (int r = threadIdx.x; r < B_GR; r += 256) {
        const float v = y[r * C + c];
        s += v; q += v * v;
    }
    __shared__ float ss[256], qq[256];
    ss[threadIdx.x] = s; qq[threadIdx.x] = q;
    __syncthreads();
    for (int off = 128; off > 0; off >>= 1) {
        if (threadIdx.x < off) {
            ss[threadIdx.x] += ss[threadIdx.x + off];
            qq[threadIdx.x] += qq[threadIdx.x + off];
        }
        __syncthreads();
    }
    if (threadIdx.x == 0) {
        const float mean = ss[0] / (float)B_GR;
        const float var  = qq[0] / (float)B_GR - mean * mean;
        st[c]     = mean;
        st[C + c] = rsqrtf(var + 1e-5f);
    }
}

__launch_bounds__(256)
__global__ void dense2_kernel(const float* __restrict__ y1,
                              const float* __restrict__ st1,
                              const float* __restrict__ g1,
                              const float* __restrict__ be1,
                              const float* __restrict__ Wl2,
                              const float* __restrict__ bl2,
                              float*       __restrict__ y2)
{
    __shared__ float h[4 * 96];
    const int r0 = blockIdx.x * 4;
    for (int e = threadIdx.x; e < 4 * 96; e += 256) {
        const int rr = e / 96, c = e - rr * 96;
        float v = y1[(r0 + rr) * 96 + c];
        v = (v - st1[c]) * st1[96 + c] * g1[c] + be1[c];
        h[e] = fmaxf(v, 0.f);
    }
    __syncthreads();
    for (int e = threadIdx.x; e < 4 * 63; e += 256) {
        const int rr = e / 63, o = e - rr * 63;
        float acc = bl2[o];
        #pragma unroll
        for (int f = 0; f < 96; ++f) acc += h[rr * 96 + f] * Wl2[f * 63 + o];
        y2[(r0 + rr) * 63 + o] = acc;
    }
}

__launch_bounds__(320)
__global__ void dense3_kernel(const float* __restrict__ y2,
                              const float* __restrict__ st2,
                              const float* __restrict__ g2,
                              const float* __restrict__ be2,
                              const float* __restrict__ Wl3,
                              const float* __restrict__ bl3,
                              float*       __restrict__ out)
{
    __shared__ float h[2 * 63];
    const int r0 = blockIdx.x * 2;
    for (int e = threadIdx.x; e < 2 * 63; e += 320) {
        const int rr = e / 63, c = e - rr * 63;
        float v = y2[(r0 + rr) * 63 + c];
        v = (v - st2[c]) * st2[63 + c] * g2[c] + be2[c];
        h[e] = fmaxf(v, 0.f);
    }
    __syncthreads();
    for (int e = threadIdx.x; e < 2 * 138; e += 320) {
        const int rr = e / 138, o = e - rr * 138;
        float acc = bl3[o];
        #pragma unroll
        for (int f = 0; f < 63; ++f) acc += h[rr * 63 + f] * Wl3[f * 138 + o];
        out[(r0 + rr) * 138 + o] = 1.f / (1.f + __expf(-acc));
    }
}

extern "C" void kernel_launch(void* const* d_in, const int* in_sizes, int n_in,
                              void* d_out, int out_size, void* d_ws, size_t ws_size,
                              hipStream_t stream)
{
    (void)in_sizes; (void)n_in; (void)out_size; (void)ws_size;

    const float* af  = (const float*)d_in[0];
    const float* Ws1 = (const float*)d_in[1];
    const float* Wn1 = (const float*)d_in[2];
    const float* b1  = (const float*)d_in[3];
    const float* Ws2 = (const float*)d_in[4];
    const float* Wn2 = (const float*)d_in[5];
    const float* b2  = (const float*)d_in[6];
    const float* Ws3 = (const float*)d_in[7];
    const float* Wn3 = (const float*)d_in[8];
    const float* b3  = (const float*)d_in[9];
    const float* Ws4 = (const float*)d_in[10];
    const float* Wn4 = (const float*)d_in[11];
    const float* b4  = (const float*)d_in[12];
    const float* Wd2 = (const float*)d_in[13];
    const float* bd2 = (const float*)d_in[14];
    const float* Wl1 = (const float*)d_in[15];
    const float* bl1 = (const float*)d_in[16];
    const float* g1  = (const float*)d_in[17];
    const float* be1 = (const float*)d_in[18];
    const float* Wl2 = (const float*)d_in[19];
    const float* bl2 = (const float*)d_in[20];
    const float* g2  = (const float*)d_in[21];
    const float* be2 = (const float*)d_in[22];
    const float* Wl3 = (const float*)d_in[23];
    const float* bl3 = (const float*)d_in[24];
    const int*   nbr = (const int*)d_in[25];
    const int*   deg = (const int*)d_in[26];
    const int*   mem = (const int*)d_in[27];

    float* ws = (float*)d_ws;
    // Regions (floats):
    //   A: PADCAP*27  x1 (conv1-2) then x3 (conv3-4); head scratch after conv4
    //   B: PADCAP*36  x2 (conv2-3) then x4 (conv4+)
    //   D: PADCAP*20  nsum_t scratch ([FI][cap] per chunk)
    //   E: PADCAP*20  x_t scratch ([FI][cap] per chunk)
    float* A = ws;
    float* B = A + (size_t)PADCAP * 27;
    float* D = B + (size_t)PADCAP * 36;
    float* E = D + (size_t)PADCAP * 20;
    int*   idx    = (int*)(E + (size_t)PADCAP * 20);    // PADCAP
    int*   rank   = idx + PADCAP;                       // N_ATOMS
    int*   degs_s = rank + N_ATOMS;                     // PADCAP
    int4*  nbrs_s = (int4*)(degs_s + PADCAP);           // PADCAP int4 (sorted ranks)
    int4*  nbro_s = nbrs_s + PADCAP;                    // PADCAP int4 (original ids)
    int*   ctr    = (int*)(nbro_s + PADCAP);            // 16 ints

    float* x1 = A;
    float* x2 = B;
    float* x3 = A;
    float* x4 = B;
    float* p   = A;                          // head scratch reuses A (x3 dead after conv4)
    float* y1  = A + 393216;                 // B_GR*96
    float* y2  = A + 393216 + 1572864;       // B_GR*63
    float* st1 = A + 393216 + 1572864 + 1032192;        // 192
    float* st2 = st1 + 192;                              // 126

    // ---- degree-sort prep (permutation may vary run-to-run; per-atom math identical) ----
    zero_kernel<<<1, 16, 0, stream>>>(ctr);
    fill_kernel<<<PADCAP / 256, 256, 0, stream>>>(idx, degs_s);
    hist_kernel<<<1024, 256, 0, stream>>>(deg, ctr);
    offsets_kernel<<<1, 1, 0, stream>>>(ctr);
    scatter_kernel<<<(N_ATOMS + 255) / 256, 256, 0, stream>>>(deg, ctr, idx, rank, degs_s);
    nbrprep_kernel<<<(N_ATOMS + 255) / 256, 256, 0, stream>>>(nbr, rank, nbrs_s, nbro_s);

    // ---- conv stack: transpose-prep + transposed affine for ALL layers ----
    run_convT<75, 77, 15, true >(af, Ws1, Wn1, b1, nbro_s, degs_s, idx, x1, E, D, stream);
    run_convT<15, 17, 20, false>(x1, Ws2, Wn2, b2, nbrs_s, degs_s, idx, x2, E, D, stream);
    run_convT<20, 21, 27, false>(x2, Ws3, Wn3, b3, nbrs_s, degs_s, idx, x3, E, D, stream);
    run_convT<27, 29, 36, false>(x3, Ws4, Wn4, b4, nbrs_s, degs_s, idx, x4, E, D, stream);

    readout_kernel<<<B_GR, 64, 0, stream>>>(x4, rank, mem, Wd2, bd2, p);

    dense1_kernel<<<(B_GR * 96) / 256, 256, 0, stream>>>(p, Wl1, bl1, y1);
    stats_kernel<96><<<96, 256, 0, stream>>>(y1, st1);
    dense2_kernel<<<B_GR / 4, 256, 0, stream>>>(y1, st1, g1, be1, Wl2, bl2, y2);
    stats_kernel<63><<<63, 256, 0, stream>>>(y2, st2);
    dense3_kernel<<<B_GR / 2, 320, 0, stream>>>(y2, st2, g2, be2, Wl3, bl3, (float*)d_out);
}

// Round 10
// 804.928 us; speedup vs baseline: 1.4601x; 1.2297x over previous
//
#include <hip/hip_runtime.h>
#include <hip/hip_bf16.h>

#define N_ATOMS 400000
#define MAX_D   4
#define NDEG_   5
#define B_GR    16384
#define NTASK   12
#define AT      256                 // bin alignment
#define PADCAP  401408              // 1568 * 256 >= N + 5*(AT-1)

__device__ __forceinline__ float selu_f(float x) {
    const float a = 1.6732632423543772f, s = 1.0507009873554805f;
    return x > 0.f ? s * x : s * a * (__expf(x) - 1.f);
}

// ===================== degree-sort prep =====================
// ctr layout (ints): [0..4] counts, [5..9] cursor, [10..15] bin offsets
__global__ void zero_kernel(int* ctr) {
    if (threadIdx.x < 10) ctr[threadIdx.x] = 0;
}

__launch_bounds__(256)
__global__ void fill_kernel(int* idx, int* degs_s) {
    const int e = blockIdx.x * 256 + threadIdx.x;
    if (e < PADCAP) { idx[e] = -1; degs_s[e] = -1; }
}

__launch_bounds__(256)
__global__ void hist_kernel(const int* __restrict__ deg, int* ctr) {
    __shared__ int h[NDEG_];
    if (threadIdx.x < NDEG_) h[threadIdx.x] = 0;
    __syncthreads();
    for (int i = blockIdx.x * 256 + threadIdx.x; i < N_ATOMS; i += gridDim.x * 256)
        atomicAdd(&h[deg[i]], 1);
    __syncthreads();
    if (threadIdx.x < NDEG_ && h[threadIdx.x]) atomicAdd(&ctr[threadIdx.x], h[threadIdx.x]);
}

__global__ void offsets_kernel(int* ctr) {
    if (threadIdx.x == 0) {
        int run = 0;
        for (int d = 0; d < NDEG_; ++d) {
            ctr[10 + d] = run;
            run += ctr[d];
            run = (run + AT - 1) & ~(AT - 1);
        }
        ctr[15] = run;
    }
}

// Hierarchical scatter: per-block LDS histogram -> ONE global atomicAdd per
// (block, degree) -> intra-block rank from LDS counter.
__launch_bounds__(256)
__global__ void scatter_kernel(const int* __restrict__ deg, int* ctr,
                               int* idx, int* rank, int* degs_s) {
    __shared__ int h[NDEG_];
    __shared__ int base[NDEG_];
    const int i = blockIdx.x * 256 + threadIdx.x;
    const int d = (i < N_ATOMS) ? deg[i] : -1;
    if (threadIdx.x < NDEG_) h[threadIdx.x] = 0;
    __syncthreads();
    int intra = 0;
    if (i < N_ATOMS) intra = atomicAdd(&h[d], 1);            // LDS atomic
    __syncthreads();
    if (threadIdx.x < NDEG_ && h[threadIdx.x] > 0)
        base[threadIdx.x] = atomicAdd(&ctr[5 + threadIdx.x], h[threadIdx.x]);
    __syncthreads();
    if (i < N_ATOMS) {
        const int p = ctr[10 + d] + base[d] + intra;
        idx[p] = i;
        rank[i] = p;
        degs_s[p] = d;
    }
}

// Emits BOTH sorted-rank neighbors (layers 2-4) and original-id neighbors (conv1).
__launch_bounds__(256)
__global__ void nbrprep_kernel(const int* __restrict__ nbr, const int* __restrict__ rank,
                               int4* __restrict__ nbrs_s, int4* __restrict__ nbro_s) {
    const int i = blockIdx.x * 256 + threadIdx.x;
    if (i >= N_ATOMS) return;
    const int p = rank[i];
    const int4 nb = *reinterpret_cast<const int4*>(nbr + (size_t)i * MAX_D);
    nbro_s[p] = nb;
    nbrs_s[p] = make_int4(rank[nb.x], rank[nb.y], rank[nb.z], rank[nb.w]);
}

// ===================== fully-fused conv layer =====================
// 64-atom degree-uniform tiles (64 | 256-aligned bins).
// Phase A (all 4 waves): coalesced row reads (f across lanes) of self +
//   masked 4-neighbor sum -> LDS tiles [64][FIP] (FIP odd -> 2-way = free).
//   This is exactly R9's prep gather shape (1.8 TB/s proven).
// Phase B (wave 0 only): lane = atom; acc[FO] in registers; WAVE-UNIFORM
//   scalar weight loads (SGPR operands -> 2*FO FMA per 2 ds_read, the
//   R4/R7-proven fast affine); inputs from LDS. No scratch, no transpose,
//   no second dispatch. (R5's slow variant read weights per-lane from LDS;
//   R6's failure was 77KB LDS killing occupancy -- both avoided here.)
// SCATTER_OUT (conv4): write rows to ORIGINAL atom order via idx so the
//   readout reads sequentially.
template<int FI, int FIP, int FO, bool FIRST, bool SCATTER_OUT>
__launch_bounds__(256)
__global__ void conv_fused2(const float* __restrict__ x,     // FIRST: af (orig order), else x_prev (sorted)
                            const int4*  __restrict__ nbr_,  // FIRST: original ids, else sorted ranks
                            const float* __restrict__ Ws,
                            const float* __restrict__ Wn,
                            const float* __restrict__ bias,
                            const int*   __restrict__ degs_s,
                            const int*   __restrict__ idx,
                            float*       __restrict__ outs)
{
    __shared__ float xt[64][FIP];
    __shared__ float nt[64][FIP];
    __shared__ int   s_a[64];
    __shared__ int   s_d[64];
    __shared__ int4  s_nb[64];

    const int pb = blockIdx.x * 64;
    const int dfirst = degs_s[pb];
    if (dfirst < 0) return;                       // whole tile is padding
    const int tid = threadIdx.x;

    if (tid < 64) {
        const int p = pb + tid;
        int a = FIRST ? idx[p] : p;
        s_a[tid] = (a < 0) ? 0 : a;               // padding: dummy row 0
        s_d[tid] = degs_s[p];
        s_nb[tid] = nbr_[p];
    }
    __syncthreads();

    // ---- phase A: coalesced gather into LDS ----
    for (int e = tid; e < 64 * FI; e += 256) {
        const int al = e / FI, f = e - al * FI;
        const int d = s_d[al];
        xt[al][f] = x[(size_t)s_a[al] * FI + f];
        float s = 0.f;
        if (d > 0) {
            const int4 nb = s_nb[al];
            s += x[(size_t)nb.x * FI + f];
            if (d > 1) s += x[(size_t)nb.y * FI + f];
            if (d > 2) s += x[(size_t)nb.z * FI + f];
            if (d > 3) s += x[(size_t)nb.w * FI + f];
        }
        nt[al][f] = s;
    }
    __syncthreads();

    // ---- phase B: wave 0, lane = atom, scalar weights ----
    if (tid < 64) {
        const int d = __builtin_amdgcn_readfirstlane(dfirst);
        const float* __restrict__ wsd = Ws + d * FI * FO;
        const float* __restrict__ wnd = Wn + d * FI * FO;
        const float* __restrict__ bb  = bias + d * FO;

        float acc[FO];
        #pragma unroll
        for (int o = 0; o < FO; ++o) acc[o] = bb[o];

        for (int f = 0; f < FI; ++f) {
            const float xv = xt[tid][f];
            const float nv = nt[tid][f];
            const float* __restrict__ wsf = wsd + f * FO;
            const float* __restrict__ wnf = wnd + f * FO;
            #pragma unroll
            for (int o = 0; o < FO; ++o)
                acc[o] = fmaf(xv, wsf[o], fmaf(nv, wnf[o], acc[o]));
        }

        int row; bool store;
        if (SCATTER_OUT) { row = idx[pb + tid]; store = (row >= 0); }
        else             { row = pb + tid;      store = true; }
        if (store) {
            float* __restrict__ orow = outs + (size_t)row * FO;
            #pragma unroll
            for (int o = 0; o < FO; ++o) orow[o] = selu_f(acc[o]);
        }
    }
}

// ===================== GraphGather readout + softmax head =====================
// x4o is in ORIGINAL atom order -> sequential row reads per graph segment.
__launch_bounds__(64)
__global__ void readout_kernel(const float* __restrict__ x4o,
                               const int*   __restrict__ mem,
                               const float* __restrict__ Wd2,
                               const float* __restrict__ bd2,
                               float*       __restrict__ p)
{
    const int g = blockIdx.x;
    const int t = threadIdx.x;

    int lo = 0, hi = N_ATOMS;                    // lower_bound(g)
    while (lo < hi) { int mid = (lo + hi) >> 1; if (mem[mid] < g) lo = mid + 1; else hi = mid; }
    int lo2 = lo, hi2 = N_ATOMS;                 // lower_bound(g+1)
    while (lo2 < hi2) { int mid = (lo2 + hi2) >> 1; if (mem[mid] < g + 1) lo2 = mid + 1; else hi2 = mid; }

    __shared__ float r[72];
    if (t < 36) {
        float s = 0.f, m = -3.4e38f;
        for (int a = lo; a < lo2; ++a) {
            float v = x4o[(size_t)a * 36 + t];
            s += v;
            m = fmaxf(m, v);
        }
        if (lo2 == lo) m = 0.f;                  // empty graph -> 0
        r[t]      = selu_f(s);
        r[36 + t] = selu_f(m);
    }
    __syncthreads();
    if (t < 24) {
        float acc = bd2[t];
        #pragma unroll
        for (int f = 0; f < 72; ++f) acc += r[f] * Wd2[f * 24 + t];
        float part = __shfl_xor(acc, 1);
        p[g * 24 + t] = 1.f / (1.f + __expf(part - acc));
    }
}

__launch_bounds__(256)
__global__ void dense1_kernel(const float* __restrict__ p,
                              const float* __restrict__ Wl1,
                              const float* __restrict__ bl1,
                              float*       __restrict__ y1)
{
    const int idx = blockIdx.x * 256 + threadIdx.x;
    if (idx >= B_GR * 96) return;
    const int row = idx / 96, c = idx - row * 96;
    float acc = bl1[c];
    const float* pr = p + row * 24;
    #pragma unroll
    for (int f = 0; f < 24; ++f) acc += pr[f] * Wl1[f * 96 + c];
    y1[idx] = acc;
}

template<int C>
__launch_bounds__(256)
__global__ void stats_kernel(const float* __restrict__ y, float* __restrict__ st)
{
    const int c = blockIdx.x;
    float s = 0.f, q = 0.f;
    for (int r = threadIdx.x; r < B_GR; r += 256) {
        const float v = y[r * C + c];
        s += v; q += v * v;
    }
    __shared__ float ss[256], qq[256];
    ss[threadIdx.x] = s; qq[threadIdx.x] = q;
    __syncthreads();
    for (int off = 128; off > 0; off >>= 1) {
        if (threadIdx.x < off) {
            ss[threadIdx.x] += ss[threadIdx.x + off];
            qq[threadIdx.x] += qq[threadIdx.x + off];
        }
        __syncthreads();
    }
    if (threadIdx.x == 0) {
        const float mean = ss[0] / (float)B_GR;
        const float var  = qq[0] / (float)B_GR - mean * mean;
        st[c]     = mean;
        st[C + c] = rsqrtf(var + 1e-5f);
    }
}

__launch_bounds__(256)
__global__ void dense2_kernel(const float* __restrict__ y1,
                              const float* __restrict__ st1,
                              const float* __restrict__ g1,
                              const float* __restrict__ be1,
                              const float* __restrict__ Wl2,
                              const float* __restrict__ bl2,
                              float*       __restrict__ y2)
{
    __shared__ float h[4 * 96];
    const int r0 = blockIdx.x * 4;
    for (int e = threadIdx.x; e < 4 * 96; e += 256) {
        const int rr = e / 96, c = e - rr * 96;
        float v = y1[(r0 + rr) * 96 + c];
        v = (v - st1[c]) * st1[96 + c] * g1[c] + be1[c];
        h[e] = fmaxf(v, 0.f);
    }
    __syncthreads();
    for (int e = threadIdx.x; e < 4 * 63; e += 256) {
        const int rr = e / 63, o = e - rr * 63;
        float acc = bl2[o];
        #pragma unroll
        for (int f = 0; f < 96; ++f) acc += h[rr * 96 + f] * Wl2[f * 63 + o];
        y2[(r0 + rr) * 63 + o] = acc;
    }
}

__launch_bounds__(320)
__global__ void dense3_kernel(const float* __restrict__ y2,
                              const float* __restrict__ st2,
                              const float* __restrict__ g2,
                              const float* __restrict__ be2,
                              const float* __restrict__ Wl3,
                              const float* __restrict__ bl3,
                              float*       __restrict__ out)
{
    __shared__ float h[2 * 63];
    const int r0 = blockIdx.x * 2;
    for (int e = threadIdx.x; e < 2 * 63; e += 320) {
        const int rr = e / 63, c = e - rr * 63;
        float v = y2[(r0 + rr) * 63 + c];
        v = (v - st2[c]) * st2[63 + c] * g2[c] + be2[c];
        h[e] = fmaxf(v, 0.f);
    }
    __syncthreads();
    for (int e = threadIdx.x; e < 2 * 138; e += 320) {
        const int rr = e / 138, o = e - rr * 138;
        float acc = bl3[o];
        #pragma unroll
        for (int f = 0; f < 63; ++f) acc += h[rr * 63 + f] * Wl3[f * 138 + o];
        out[(r0 + rr) * 138 + o] = 1.f / (1.f + __expf(-acc));
    }
}

extern "C" void kernel_launch(void* const* d_in, const int* in_sizes, int n_in,
                              void* d_out, int out_size, void* d_ws, size_t ws_size,
                              hipStream_t stream)
{
    (void)in_sizes; (void)n_in; (void)out_size; (void)ws_size;

    const float* af  = (const float*)d_in[0];
    const float* Ws1 = (const float*)d_in[1];
    const float* Wn1 = (const float*)d_in[2];
    const float* b1  = (const float*)d_in[3];
    const float* Ws2 = (const float*)d_in[4];
    const float* Wn2 = (const float*)d_in[5];
    const float* b2  = (const float*)d_in[6];
    const float* Ws3 = (const float*)d_in[7];
    const float* Wn3 = (const float*)d_in[8];
    const float* b3  = (const float*)d_in[9];
    const float* Ws4 = (const float*)d_in[10];
    const float* Wn4 = (const float*)d_in[11];
    const float* b4  = (const float*)d_in[12];
    const float* Wd2 = (const float*)d_in[13];
    const float* bd2 = (const float*)d_in[14];
    const float* Wl1 = (const float*)d_in[15];
    const float* bl1 = (const float*)d_in[16];
    const float* g1  = (const float*)d_in[17];
    const float* be1 = (const float*)d_in[18];
    const float* Wl2 = (const float*)d_in[19];
    const float* bl2 = (const float*)d_in[20];
    const float* g2  = (const float*)d_in[21];
    const float* be2 = (const float*)d_in[22];
    const float* Wl3 = (const float*)d_in[23];
    const float* bl3 = (const float*)d_in[24];
    const int*   nbr = (const int*)d_in[25];
    const int*   deg = (const int*)d_in[26];
    const int*   mem = (const int*)d_in[27];

    float* ws = (float*)d_ws;
    // Regions (floats):
    //   A: PADCAP*27  x1 (sorted), then x3 (sorted), then head scratch
    //   B: PADCAP*36  x2 (sorted), then x4o (ORIGINAL atom order)
    float* A = ws;
    float* B = A + (size_t)PADCAP * 27;
    int*   idx    = (int*)(B + (size_t)PADCAP * 36);    // PADCAP
    int*   rank   = idx + PADCAP;                       // N_ATOMS
    int*   degs_s = rank + N_ATOMS;                     // PADCAP
    int4*  nbrs_s = (int4*)(degs_s + PADCAP);           // PADCAP int4 (sorted ranks)
    int4*  nbro_s = nbrs_s + PADCAP;                    // PADCAP int4 (original ids)
    int*   ctr    = (int*)(nbro_s + PADCAP);            // 16 ints

    float* x1  = A;
    float* x2  = B;
    float* x3  = A;
    float* x4o = B;                          // original-order conv4 output
    float* p   = A;                          // head scratch reuses A (x3 dead after conv4)
    float* y1  = A + 393216;                 // B_GR*96
    float* y2  = A + 393216 + 1572864;       // B_GR*63
    float* st1 = A + 393216 + 1572864 + 1032192;        // 192
    float* st2 = st1 + 192;                              // 126

    // ---- degree-sort prep (permutation may vary run-to-run; per-atom math identical) ----
    zero_kernel<<<1, 16, 0, stream>>>(ctr);
    fill_kernel<<<PADCAP / 256, 256, 0, stream>>>(idx, degs_s);
    hist_kernel<<<1024, 256, 0, stream>>>(deg, ctr);
    offsets_kernel<<<1, 1, 0, stream>>>(ctr);
    scatter_kernel<<<(N_ATOMS + 255) / 256, 256, 0, stream>>>(deg, ctr, idx, rank, degs_s);
    nbrprep_kernel<<<(N_ATOMS + 255) / 256, 256, 0, stream>>>(nbr, rank, nbrs_s, nbro_s);

    // ---- fully-fused conv stack (one kernel per layer, no scratch) ----
    // LDS: conv1 40.9KB (4 blk/CU), conv2 10.2KB, conv3 12.3KB, conv4 14.8KB (8 blk/CU)
    conv_fused2<75, 77, 15, true,  false><<<PADCAP / 64, 256, 0, stream>>>
        (af, nbro_s, Ws1, Wn1, b1, degs_s, idx, x1);
    conv_fused2<15, 17, 20, false, false><<<PADCAP / 64, 256, 0, stream>>>
        (x1, nbrs_s, Ws2, Wn2, b2, degs_s, idx, x2);
    conv_fused2<20, 21, 27, false, false><<<PADCAP / 64, 256, 0, stream>>>
        (x2, nbrs_s, Ws3, Wn3, b3, degs_s, idx, x3);
    conv_fused2<27, 29, 36, false, true ><<<PADCAP / 64, 256, 0, stream>>>
        (x3, nbrs_s, Ws4, Wn4, b4, degs_s, idx, x4o);

    readout_kernel<<<B_GR, 64, 0, stream>>>(x4o, mem, Wd2, bd2, p);

    dense1_kernel<<<(B_GR * 96) / 256, 256, 0, stream>>>(p, Wl1, bl1, y1);
    stats_kernel<96><<<96, 256, 0, stream>>>(y1, st1);
    dense2_kernel<<<B_GR / 4, 256, 0, stream>>>(y1, st1, g1, be1, Wl2, bl2, y2);
    stats_kernel<63><<<63, 256, 0, stream>>>(y2, st2);
    dense3_kernel<<<B_GR / 2, 320, 0, stream>>>(y2, st2, g2, be2, Wl3, bl3, (float*)d_out);
}